// Round 3
// baseline (390.926 us; speedup 1.0000x reference)
//
#include <hip/hip_runtime.h>
#include <math.h>

// ---------------------------------------------------------------------------
// MultiHead_CrossAttention: out = (softmax_heads((y@Wq)·(x@Wkv_k)^T/8) @ Wkv_v) @ Wo
// B=4 L=4096 D=1024 H=16 hd=64.
// R6: GEMM switched 16x16x32 -> 32x32x16 MFMA (ceiling 2075 -> 2495 TF,
//     half the MFMA instructions) and merged each K-half to ONE phase
//     (12 ds_read -> barrier -> lgkm -> 16 MFMA -> vmcnt(8) -> barrier):
//     2 barriers/half instead of 4. Ring of 4 K-half slots kept from R5.
// ---------------------------------------------------------------------------

typedef __attribute__((ext_vector_type(8))) short bf16x8;
typedef __attribute__((ext_vector_type(4))) float f32x4;
typedef __attribute__((ext_vector_type(16))) float f32x16;

__device__ __forceinline__ float b2f(short s) {
    union { unsigned u; float f; } x;
    x.u = ((unsigned)(unsigned short)s) << 16;
    return x.f;
}
__device__ __forceinline__ short f2b(float f) {
    union { float f; unsigned u; } x;
    x.f = f;
    unsigned r = (x.u + 0x7FFFu + ((x.u >> 16) & 1u)) >> 16;  // RNE
    return (short)r;
}

// ---- cast fp32 -> bf16 for two tensors in one launch ----------------------
__global__ __launch_bounds__(256) void cast2_f32_bf16(
    const float* __restrict__ in0, short* __restrict__ out0,
    const float* __restrict__ in1, short* __restrict__ out1, int n) {
    int i = (blockIdx.x * 256 + threadIdx.x) * 4;
    const float* in = in0;
    short* out = out0;
    if (i >= n) {
        i -= n;
        in = in1;
        out = out1;
    }
    float4 v = *(const float4*)(in + i);
    short4 o;
    o.x = f2b(v.x); o.y = f2b(v.y); o.z = f2b(v.z); o.w = f2b(v.w);
    *(short4*)(out + i) = o;
}

// ---- transpose + cast: W[K][N] fp32 -> Wt[N][K] bf16 ----------------------
__global__ __launch_bounds__(256) void transpose_cast2(
    const float* __restrict__ W0, short* __restrict__ Wt0,
    const float* __restrict__ W1, short* __restrict__ Wt1, int K, int N) {
    const float* W = blockIdx.z ? W1 : W0;
    short* Wt = blockIdx.z ? Wt1 : Wt0;
    __shared__ float tile[32][33];
    int tx = threadIdx.x;
    int ty = threadIdx.y;
    int bx = blockIdx.x * 32;
    int by = blockIdx.y * 32;
#pragma unroll
    for (int j = 0; j < 32; j += 8)
        tile[ty + j][tx] = W[(size_t)(by + ty + j) * N + bx + tx];
    __syncthreads();
#pragma unroll
    for (int j = 0; j < 32; j += 8)
        Wt[(size_t)(bx + ty + j) * K + by + tx] = f2b(tile[tx][ty + j]);
}

// ---- bf16 MFMA GEMM, 256x256 tile, 32x32x16, 4-slot K-half ring -----------
// 512 threads = 8 waves (2 row x 4 col), each wave owns 128x64 of C as a
// 4x2 grid of 32x32 frags (f32x16 each, 128 acc VGPR). LDS: 4 ring slots x
// (A[256][32] + B[256][32]) bf16 = 128 KiB; slot s holds K-half m (m&3==s).
// Per K-half ONE phase: 12 ds_read_b128 (8 A + 4 B) + 4 global_load_lds
// (half m+3) -> s_barrier -> lgkmcnt(0) -> setprio(1) 16 MFMA setprio(0)
// -> vmcnt(8) (half m+1 landed; 8 stay in flight) -> s_barrier.
// Swizzle (both sides, rule 21): 16B-slot of k-chunk c in row r is
// c ^ ((r>>1)&3); staging pre-permutes the global source column, reads XOR
// the slot. Measured 0 bank conflicts (R1/R5).
// Frag layouts 32x32x16 bf16: A/B: row|col = lane&31, k = (lane>>5)*8+j.
// C/D: col = lane&31, row = (reg&3) + 8*(reg>>2) + 4*(lane>>5)  [m74/m101].
#define BM 256
#define BN 256

#define GLD16(g, l)                                           \
    __builtin_amdgcn_global_load_lds(                         \
        (const __attribute__((address_space(1))) void*)(g),   \
        (__attribute__((address_space(3))) void*)(l), 16, 0, 0)

template <int OUT_BF16>
__global__ __launch_bounds__(512, 2) void gemm_bt(
    const short* __restrict__ A,    // [M][K] bf16
    const short* __restrict__ Bt,   // [N][K] bf16 (pre-transposed weight)
    const float* __restrict__ bias, // [N]
    void* __restrict__ Cout,        // [M][N] bf16 or fp32
    int M, int N, int K) {
    __shared__ __align__(16) short lds[65536];  // 128 KiB

    const int tid = threadIdx.x;

    // T1: XCD-chunked swizzle (nwg % 8 == 0 for all our shapes)
    const int NX = gridDim.x;
    const int nwg = NX * gridDim.y;
    int lin = blockIdx.y * NX + blockIdx.x;
    lin = (lin & 7) * (nwg >> 3) + (lin >> 3);
    const int bn = (lin % NX) * BN;
    const int bm = (lin / NX) * BM;

    const int lane = tid & 63;
    const int wave = tid >> 6;
    const int wr = wave >> 2;  // 0..1: 128-row block
    const int wc = wave & 3;   // 0..3: 64-col block
    const int l31 = lane & 31;
    const int kh = lane >> 5;
    const int swz = (l31 >> 1) & 3;
    const int s0 = (kh ^ swz) << 3;        // 16B-slot offset (shorts), ks=0
    const int s1 = ((2 | kh) ^ swz) << 3;  // ks=1
    // frag row bases (shorts within an A/B half-tile)
    const int arow = (wr * 128 + l31) * 32;  // + mi*1024
    const int brow = (wc * 64 + l31) * 32;   // + nj*1024

    // staging: thread tid covers row tid/4 (and +128), 16B-slot tid&3;
    // source k-chunk = (tid&3)^((tid>>3)&3) (inverse of read swizzle)
    const int srow = tid >> 2;
    const int sslot = ((tid & 3) ^ ((tid >> 3) & 3)) * 8;
    const short* agp = A + (size_t)(bm + srow) * K + sslot;
    const short* bgp = Bt + (size_t)(bn + srow) * K + sslot;
    const size_t qstep = (size_t)128 * K;
    char* const lbase = (char*)lds;
    const int dst = tid * 16;

    f32x16 acc[4][2];
#pragma unroll
    for (int i = 0; i < 4; ++i)
#pragma unroll
        for (int j = 0; j < 2; ++j)
#pragma unroll
            for (int e = 0; e < 16; ++e) acc[i][j][e] = 0.f;

    // prologue: issue halves 0,1,2 (12 loads, oldest-first)
#pragma unroll
    for (int h = 0; h < 3; ++h) {
        const int kk = h << 5;
        GLD16(agp + kk, lbase + h * 32768 + dst);
        GLD16(agp + kk + qstep, lbase + h * 32768 + 8192 + dst);
        GLD16(bgp + kk, lbase + h * 32768 + 16384 + dst);
        GLD16(bgp + kk + qstep, lbase + h * 32768 + 24576 + dst);
    }
    asm volatile("s_waitcnt vmcnt(8)" ::: "memory");  // half 0 landed
    __builtin_amdgcn_s_barrier();

    const int NH = K >> 5;  // 32 K-halves
    for (int mm = 0; mm < NH; mm += 4) {
#pragma unroll
        for (int u = 0; u < 4; ++u) {
            const int m = mm + u;
            const int slot = u;             // (mm+u)&3 == u (mm%4==0)
            const int wslot = (u + 3) & 3;  // ring slot for half m+3
            // tail: re-issue last half's (L2-hot) addresses into the dead
            // slot to keep vmcnt counts uniform
            const int kis = ((m + 3 < NH) ? (m + 3) : (NH - 1)) << 5;
            const short* la = &lds[slot * 16384 + arow];
            const short* lb = &lds[slot * 16384 + 8192 + brow];
            bf16x8 af[4][2], bfr[2][2];
            // ---- single phase: 12 ds_read + 4 gld_lds ----
#pragma unroll
            for (int mi = 0; mi < 4; ++mi) {
                af[mi][0] = *(const bf16x8*)(la + mi * 1024 + s0);
                af[mi][1] = *(const bf16x8*)(la + mi * 1024 + s1);
            }
#pragma unroll
            for (int nj = 0; nj < 2; ++nj) {
                bfr[nj][0] = *(const bf16x8*)(lb + nj * 1024 + s0);
                bfr[nj][1] = *(const bf16x8*)(lb + nj * 1024 + s1);
            }
            GLD16(agp + kis, lbase + wslot * 32768 + dst);
            GLD16(agp + kis + qstep, lbase + wslot * 32768 + 8192 + dst);
            GLD16(bgp + kis, lbase + wslot * 32768 + 16384 + dst);
            GLD16(bgp + kis + qstep, lbase + wslot * 32768 + 24576 + dst);
            __builtin_amdgcn_sched_barrier(0);
            __builtin_amdgcn_s_barrier();
            asm volatile("s_waitcnt lgkmcnt(0)" ::: "memory");
            __builtin_amdgcn_sched_barrier(0);
            __builtin_amdgcn_s_setprio(1);
#pragma unroll
            for (int ks = 0; ks < 2; ++ks)
#pragma unroll
                for (int mi = 0; mi < 4; ++mi)
#pragma unroll
                    for (int nj = 0; nj < 2; ++nj)
                        acc[mi][nj] = __builtin_amdgcn_mfma_f32_32x32x16_bf16(
                            af[mi][ks], bfr[nj][ks], acc[mi][nj], 0, 0, 0);
            __builtin_amdgcn_s_setprio(0);
            // retire half m+1 (issued 3 phases ago); keep 8 in flight
            asm volatile("s_waitcnt vmcnt(8)" ::: "memory");
            __builtin_amdgcn_s_barrier();
        }
    }

    // epilogue: col = bn + wc*64 + nj*32 + l31,
    //           row = bm + wr*128 + mi*32 + (reg&3) + 8*(reg>>2) + 4*kh
    float bv[2];
#pragma unroll
    for (int nj = 0; nj < 2; ++nj) bv[nj] = bias[bn + wc * 64 + nj * 32 + l31];
#pragma unroll
    for (int mi = 0; mi < 4; ++mi) {
#pragma unroll
        for (int q = 0; q < 4; ++q) {
#pragma unroll
            for (int rr = 0; rr < 4; ++rr) {
                const int row = bm + wr * 128 + mi * 32 + rr + 8 * q + 4 * kh;
#pragma unroll
                for (int nj = 0; nj < 2; ++nj) {
                    const int col = bn + wc * 64 + nj * 32 + l31;
                    float v = acc[mi][nj][q * 4 + rr] + bv[nj];
                    if (OUT_BF16)
                        ((short*)Cout)[(size_t)row * N + col] = f2b(v);
                    else
                        ((float*)Cout)[(size_t)row * N + col] = v;
                }
            }
        }
    }
    // drain tail garbage-stages before LDS dealloc at wave exit
    asm volatile("s_waitcnt vmcnt(0)" ::: "memory");
}

// ---- attention over heads axis, one wave per position ---------------------
__global__ __launch_bounds__(256) void attn_kernel(
    const short* __restrict__ Q, const short* __restrict__ KV,
    short* __restrict__ VAL) {
    const int wave = threadIdx.x >> 6;
    const int lane = threadIdx.x & 63;
    const size_t p = (size_t)blockIdx.x * 4 + wave;
    const int dq = lane & 3;

    const bf16x8* qp = (const bf16x8*)(Q + p * 1024 + (size_t)lane * 16);
    bf16x8 q0 = qp[0], q1 = qp[1];
    float q[16];
#pragma unroll
    for (int j = 0; j < 8; ++j) {
        q[j] = b2f(q0[j]);
        q[8 + j] = b2f(q1[j]);
    }

    const short* kvb = KV + p * 2048;

    float s[16];
#pragma unroll
    for (int g = 0; g < 16; ++g) {
        const bf16x8* kp = (const bf16x8*)(kvb + g * 128 + dq * 16);
        bf16x8 k0 = kp[0], k1 = kp[1];
        float d = 0.f;
#pragma unroll
        for (int j = 0; j < 8; ++j) {
            d += q[j] * b2f(k0[j]);
            d += q[8 + j] * b2f(k1[j]);
        }
        s[g] = d;
    }
    float mx = -1e30f;
#pragma unroll
    for (int g = 0; g < 16; ++g) {
        s[g] += __shfl_xor(s[g], 1, 64);
        s[g] += __shfl_xor(s[g], 2, 64);
        s[g] *= 0.125f;
        mx = fmaxf(mx, s[g]);
    }
    float ssum = 0.f;
#pragma unroll
    for (int g = 0; g < 16; ++g) {
        s[g] = __expf(s[g] - mx);
        ssum += s[g];
    }
    const float inv = 1.0f / ssum;

    float vo[16];
#pragma unroll
    for (int j = 0; j < 16; ++j) vo[j] = 0.f;
#pragma unroll
    for (int g = 0; g < 16; ++g) {
        const float w = s[g] * inv;
        const bf16x8* vp = (const bf16x8*)(kvb + g * 128 + 64 + dq * 16);
        bf16x8 v0 = vp[0], v1 = vp[1];
#pragma unroll
        for (int j = 0; j < 8; ++j) {
            vo[j] += w * b2f(v0[j]);
            vo[8 + j] += w * b2f(v1[j]);
        }
    }

    bf16x8 o0, o1;
#pragma unroll
    for (int j = 0; j < 8; ++j) {
        o0[j] = f2b(vo[j]);
        o1[j] = f2b(vo[8 + j]);
    }
    bf16x8* op = (bf16x8*)(VAL + p * 1024 + (size_t)lane * 16);
    op[0] = o0;
    op[1] = o1;
}

// ---------------------------------------------------------------------------
extern "C" void kernel_launch(void* const* d_in, const int* in_sizes, int n_in,
                              void* d_out, int out_size, void* d_ws,
                              size_t ws_size, hipStream_t stream) {
    const float* x = (const float*)d_in[0];
    const float* y = (const float*)d_in[1];
    const float* Wkv = (const float*)d_in[2];
    const float* bkv = (const float*)d_in[3];
    const float* Wq = (const float*)d_in[4];
    const float* bq = (const float*)d_in[5];
    const float* Wo = (const float*)d_in[6];
    const float* bo = (const float*)d_in[7];
    float* out = (float*)d_out;

    const int D = 1024;
    const int M = 16384;  // B*L

    // workspace layout (142.6 MB total)
    char* ws = (char*)d_ws;
    short* Xb = (short*)(ws);                      // M*D bf16      (33.5 MB)
    short* Yb = (short*)(ws + 33554432);           // M*D bf16      (33.5 MB)
    short* Wkvt = (short*)(ws + 67108864);         // 2D*D bf16     (4 MB)
    short* Wqt = (short*)(ws + 71303168);          // D*D bf16      (2 MB)
    short* Wot = (short*)(ws + 73400320);          // D*D bf16      (2 MB)
    short* KV = (short*)(ws + 75497472);           // M*2D bf16     (67 MB)
    short* Q = Xb;    // Xb dead after kv GEMM
    short* VAL = Yb;  // Yb dead after q GEMM

    const int n = M * D;  // 16777216

    cast2_f32_bf16<<<2 * n / 1024, 256, 0, stream>>>(x, Xb, y, Yb, n);
    transpose_cast2<<<dim3(2 * D / 32, D / 32, 1), dim3(32, 8), 0, stream>>>(
        Wkv, Wkvt, (const float*)0, (short*)0, D, 2 * D);
    transpose_cast2<<<dim3(D / 32, D / 32, 2), dim3(32, 8), 0, stream>>>(
        Wq, Wqt, Wo, Wot, D, D);

    // kv = x @ Wkv + bkv   [16384 x 2048] bf16
    gemm_bt<1><<<dim3(2 * D / BN, M / BM), 512, 0, stream>>>(
        Xb, Wkvt, bkv, KV, M, 2 * D, D);
    // q = y @ Wq + bq      [16384 x 1024] bf16 (into Xb slot)
    gemm_bt<1><<<dim3(D / BN, M / BM), 512, 0, stream>>>(
        Yb, Wqt, bq, Q, M, D, D);
    // attention over heads -> VAL (into Yb slot)
    attn_kernel<<<M / 4, 256, 0, stream>>>(Q, KV, VAL);
    // out = val @ Wo + bo  [16384 x 1024] fp32
    gemm_bt<0><<<dim3(D / BN, M / BM), 512, 0, stream>>>(
        VAL, Wot, bo, out, M, D, D);
}

// Round 4
// 377.618 us; speedup vs baseline: 1.0352x; 1.0352x over previous
//
#include <hip/hip_runtime.h>
#include <math.h>

// ---------------------------------------------------------------------------
// MultiHead_CrossAttention: out = (softmax_heads((y@Wq)·(x@Wkv_k)^T/8) @ Wkv_v) @ Wo
// B=4 L=4096 D=1024 H=16 hd=64.
// R7: (a) rotation LDS swizzle slot(r,c) = (rho(c) + (r>>1)&3)&3,
//     rho=(0,2,1,3) -- conflict-free for 32x32 frag reads under both the
//     consecutive-8-lane and paired-half-wave bank-group models (R6's XOR
//     swizzle collided kh-pairs: 6.29M conflicts). (b) ONE barrier per
//     K-half (ring slot m+3 == m-1 mod 4 is protected by the previous
//     phase's end barrier); G-issue before MFMAs; ks0/ks1 ds_reads split
//     with counted lgkmcnt(6) so ks0 MFMAs hide ks1 read latency.
// ---------------------------------------------------------------------------

typedef __attribute__((ext_vector_type(8))) short bf16x8;
typedef __attribute__((ext_vector_type(4))) float f32x4;
typedef __attribute__((ext_vector_type(16))) float f32x16;

__device__ __forceinline__ float b2f(short s) {
    union { unsigned u; float f; } x;
    x.u = ((unsigned)(unsigned short)s) << 16;
    return x.f;
}
__device__ __forceinline__ short f2b(float f) {
    union { float f; unsigned u; } x;
    x.f = f;
    unsigned r = (x.u + 0x7FFFu + ((x.u >> 16) & 1u)) >> 16;  // RNE
    return (short)r;
}

// ---- cast fp32 -> bf16 for two tensors in one launch ----------------------
__global__ __launch_bounds__(256) void cast2_f32_bf16(
    const float* __restrict__ in0, short* __restrict__ out0,
    const float* __restrict__ in1, short* __restrict__ out1, int n) {
    int i = (blockIdx.x * 256 + threadIdx.x) * 4;
    const float* in = in0;
    short* out = out0;
    if (i >= n) {
        i -= n;
        in = in1;
        out = out1;
    }
    float4 v = *(const float4*)(in + i);
    short4 o;
    o.x = f2b(v.x); o.y = f2b(v.y); o.z = f2b(v.z); o.w = f2b(v.w);
    *(short4*)(out + i) = o;
}

// ---- transpose + cast: W[K][N] fp32 -> Wt[N][K] bf16 ----------------------
__global__ __launch_bounds__(256) void transpose_cast2(
    const float* __restrict__ W0, short* __restrict__ Wt0,
    const float* __restrict__ W1, short* __restrict__ Wt1, int K, int N) {
    const float* W = blockIdx.z ? W1 : W0;
    short* Wt = blockIdx.z ? Wt1 : Wt0;
    __shared__ float tile[32][33];
    int tx = threadIdx.x;
    int ty = threadIdx.y;
    int bx = blockIdx.x * 32;
    int by = blockIdx.y * 32;
#pragma unroll
    for (int j = 0; j < 32; j += 8)
        tile[ty + j][tx] = W[(size_t)(by + ty + j) * N + bx + tx];
    __syncthreads();
#pragma unroll
    for (int j = 0; j < 32; j += 8)
        Wt[(size_t)(bx + ty + j) * K + by + tx] = f2b(tile[tx][ty + j]);
}

// ---- bf16 MFMA GEMM, 256x256 tile, 32x32x16, 4-slot K-half ring -----------
// 512 threads = 8 waves (2 row x 4 col), each wave owns 128x64 of C as a
// 4x2 grid of 32x32 frags. LDS: 4 ring slots x (A[256][32] + B[256][32])
// bf16 = 128 KiB; slot s holds K-half m (m&3==s).
// Per K-half ONE phase, ONE barrier:
//   6 ds_read (ks=0 frags) | 6 ds_read (ks=1) | 4 global_load_lds (half m+3
//   -> slot (m+3)&3, safe: that slot's readers finished before the previous
//   phase's end barrier) | lgkmcnt(6) -> 8 MFMA ks0 | lgkmcnt(0) -> 8 MFMA
//   ks1 | vmcnt(8) (half m+1 landed) | s_barrier (publishes both).
// Swizzle (both sides, rule 21): chunk c (16B) of row r lives at 16B-slot
// (rho(c) + ((r>>1)&3)) & 3, rho = (0,2,1,3). Per-row bijective (staging:
// thread's source chunk = rho((t - u_s)&3)); every 8-lane service group of
// each ds_read_b128 covers all 32 banks exactly once (hand-verified for
// ks0/ks1 x kh0/kh1), incl. the kh-paired groups that broke R6.
// Frag layouts 32x32x16 bf16: A/B: row|col = lane&31, k = (lane>>5)*8+j.
// C/D: col = lane&31, row = (reg&3) + 8*(reg>>2) + 4*(lane>>5)  [m74/m101].
#define BM 256
#define BN 256

#define GLD16(g, l)                                           \
    __builtin_amdgcn_global_load_lds(                         \
        (const __attribute__((address_space(1))) void*)(g),   \
        (__attribute__((address_space(3))) void*)(l), 16, 0, 0)

template <int OUT_BF16>
__global__ __launch_bounds__(512, 2) void gemm_bt(
    const short* __restrict__ A,    // [M][K] bf16
    const short* __restrict__ Bt,   // [N][K] bf16 (pre-transposed weight)
    const float* __restrict__ bias, // [N]
    void* __restrict__ Cout,        // [M][N] bf16 or fp32
    int M, int N, int K) {
    __shared__ __align__(16) short lds[65536];  // 128 KiB

    const int tid = threadIdx.x;

    // T1: XCD-chunked swizzle (nwg % 8 == 0 for all our shapes)
    const int NX = gridDim.x;
    const int nwg = NX * gridDim.y;
    int lin = blockIdx.y * NX + blockIdx.x;
    lin = (lin & 7) * (nwg >> 3) + (lin >> 3);
    const int bn = (lin % NX) * BN;
    const int bm = (lin / NX) * BM;

    const int lane = tid & 63;
    const int wave = tid >> 6;
    const int wr = wave >> 2;  // 0..1: 128-row block
    const int wc = wave & 3;   // 0..3: 64-col block
    const int l31 = lane & 31;
    const int kh = lane >> 5;
    const int u = (l31 >> 1) & 3;
    // read slots: ks=0 -> chunk kh, rho = 2*kh; ks=1 -> chunk 2+kh, rho=1+2kh
    const int s0 = ((u + (kh << 1)) & 3) << 3;
    const int s1 = ((u + 1 + (kh << 1)) & 3) << 3;
    // frag row bases (shorts within an A/B half-tile)
    const int arow = (wr * 128 + l31) * 32;  // + mi*1024
    const int brow = (wc * 64 + l31) * 32;   // + nj*1024

    // staging: thread tid writes row tid/4 (and +128) 16B-slot t=tid&3;
    // source chunk c = rho((t - u_s)&3), u_s = (tid>>3)&3 (same for +128)
    const int srow = tid >> 2;
    {
        // nothing
    }
    const int t_ = tid & 3;
    const int us_ = (tid >> 3) & 3;
    const int d_ = (t_ - us_) & 3;
    const int c_ = (d_ == 1) ? 2 : (d_ == 2 ? 1 : d_);  // rho (involution)
    const int sslot = c_ * 8;
    const short* agp = A + (size_t)(bm + srow) * K + sslot;
    const short* bgp = Bt + (size_t)(bn + srow) * K + sslot;
    const size_t qstep = (size_t)128 * K;
    char* const lbase = (char*)lds;
    const int dst = tid * 16;

    f32x16 acc[4][2];
#pragma unroll
    for (int i = 0; i < 4; ++i)
#pragma unroll
        for (int j = 0; j < 2; ++j)
#pragma unroll
            for (int e = 0; e < 16; ++e) acc[i][j][e] = 0.f;

    // prologue: issue halves 0,1,2 (12 loads, oldest-first)
#pragma unroll
    for (int h = 0; h < 3; ++h) {
        const int kk = h << 5;
        GLD16(agp + kk, lbase + h * 32768 + dst);
        GLD16(agp + kk + qstep, lbase + h * 32768 + 8192 + dst);
        GLD16(bgp + kk, lbase + h * 32768 + 16384 + dst);
        GLD16(bgp + kk + qstep, lbase + h * 32768 + 24576 + dst);
    }
    asm volatile("s_waitcnt vmcnt(8)" ::: "memory");  // half 0 landed
    __builtin_amdgcn_s_barrier();

    const int NH = K >> 5;  // 32 K-halves
    for (int mm = 0; mm < NH; mm += 4) {
#pragma unroll
        for (int uu = 0; uu < 4; ++uu) {
            const int m = mm + uu;
            const int slot = uu;             // (mm+uu)&3 == uu
            const int wslot = (uu + 3) & 3;  // ring slot for half m+3
            // tail: re-issue last half's (L2-hot) addresses into the dead
            // slot to keep vmcnt counts uniform
            const int kis = ((m + 3 < NH) ? (m + 3) : (NH - 1)) << 5;
            const short* la = &lds[slot * 16384 + arow];
            const short* lb = &lds[slot * 16384 + 8192 + brow];
            bf16x8 af0[4], bf0[2], af1[4], bf1[2];
            // ks=0 frag reads (oldest 6)
#pragma unroll
            for (int mi = 0; mi < 4; ++mi)
                af0[mi] = *(const bf16x8*)(la + mi * 1024 + s0);
#pragma unroll
            for (int nj = 0; nj < 2; ++nj)
                bf0[nj] = *(const bf16x8*)(lb + nj * 1024 + s0);
            __builtin_amdgcn_sched_barrier(0);
            // ks=1 frag reads
#pragma unroll
            for (int mi = 0; mi < 4; ++mi)
                af1[mi] = *(const bf16x8*)(la + mi * 1024 + s1);
#pragma unroll
            for (int nj = 0; nj < 2; ++nj)
                bf1[nj] = *(const bf16x8*)(lb + nj * 1024 + s1);
            // prefetch half m+3 (overwrites slot read in phase m-1; safe:
            // previous phase's end barrier)
            GLD16(agp + kis, lbase + wslot * 32768 + dst);
            GLD16(agp + kis + qstep, lbase + wslot * 32768 + 8192 + dst);
            GLD16(bgp + kis, lbase + wslot * 32768 + 16384 + dst);
            GLD16(bgp + kis + qstep, lbase + wslot * 32768 + 24576 + dst);
            asm volatile("s_waitcnt lgkmcnt(6)" ::: "memory");  // ks0 ready
            __builtin_amdgcn_sched_barrier(0);
            __builtin_amdgcn_s_setprio(1);
#pragma unroll
            for (int mi = 0; mi < 4; ++mi)
#pragma unroll
                for (int nj = 0; nj < 2; ++nj)
                    acc[mi][nj] = __builtin_amdgcn_mfma_f32_32x32x16_bf16(
                        af0[mi], bf0[nj], acc[mi][nj], 0, 0, 0);
            asm volatile("s_waitcnt lgkmcnt(0)" ::: "memory");  // ks1 ready
            __builtin_amdgcn_sched_barrier(0);
#pragma unroll
            for (int mi = 0; mi < 4; ++mi)
#pragma unroll
                for (int nj = 0; nj < 2; ++nj)
                    acc[mi][nj] = __builtin_amdgcn_mfma_f32_32x32x16_bf16(
                        af1[mi], bf1[nj], acc[mi][nj], 0, 0, 0);
            __builtin_amdgcn_s_setprio(0);
            // retire half m+1 (for next phase's reads); 8 stay in flight
            asm volatile("s_waitcnt vmcnt(8)" ::: "memory");
            __builtin_amdgcn_s_barrier();
        }
    }

    // epilogue: col = bn + wc*64 + nj*32 + l31,
    //           row = bm + wr*128 + mi*32 + (reg&3) + 8*(reg>>2) + 4*kh
    float bv[2];
#pragma unroll
    for (int nj = 0; nj < 2; ++nj) bv[nj] = bias[bn + wc * 64 + nj * 32 + l31];
#pragma unroll
    for (int mi = 0; mi < 4; ++mi) {
#pragma unroll
        for (int q = 0; q < 4; ++q) {
#pragma unroll
            for (int rr = 0; rr < 4; ++rr) {
                const int row = bm + wr * 128 + mi * 32 + rr + 8 * q + 4 * kh;
#pragma unroll
                for (int nj = 0; nj < 2; ++nj) {
                    const int col = bn + wc * 64 + nj * 32 + l31;
                    float v = acc[mi][nj][q * 4 + rr] + bv[nj];
                    if (OUT_BF16)
                        ((short*)Cout)[(size_t)row * N + col] = f2b(v);
                    else
                        ((float*)Cout)[(size_t)row * N + col] = v;
                }
            }
        }
    }
    // drain tail garbage-stages before LDS dealloc at wave exit
    asm volatile("s_waitcnt vmcnt(0)" ::: "memory");
}

// ---- attention over heads axis, one wave per position ---------------------
__global__ __launch_bounds__(256) void attn_kernel(
    const short* __restrict__ Q, const short* __restrict__ KV,
    short* __restrict__ VAL) {
    const int wave = threadIdx.x >> 6;
    const int lane = threadIdx.x & 63;
    const size_t p = (size_t)blockIdx.x * 4 + wave;
    const int dq = lane & 3;

    const bf16x8* qp = (const bf16x8*)(Q + p * 1024 + (size_t)lane * 16);
    bf16x8 q0 = qp[0], q1 = qp[1];
    float q[16];
#pragma unroll
    for (int j = 0; j < 8; ++j) {
        q[j] = b2f(q0[j]);
        q[8 + j] = b2f(q1[j]);
    }

    const short* kvb = KV + p * 2048;

    float s[16];
#pragma unroll
    for (int g = 0; g < 16; ++g) {
        const bf16x8* kp = (const bf16x8*)(kvb + g * 128 + dq * 16);
        bf16x8 k0 = kp[0], k1 = kp[1];
        float d = 0.f;
#pragma unroll
        for (int j = 0; j < 8; ++j) {
            d += q[j] * b2f(k0[j]);
            d += q[8 + j] * b2f(k1[j]);
        }
        s[g] = d;
    }
    float mx = -1e30f;
#pragma unroll
    for (int g = 0; g < 16; ++g) {
        s[g] += __shfl_xor(s[g], 1, 64);
        s[g] += __shfl_xor(s[g], 2, 64);
        s[g] *= 0.125f;
        mx = fmaxf(mx, s[g]);
    }
    float ssum = 0.f;
#pragma unroll
    for (int g = 0; g < 16; ++g) {
        s[g] = __expf(s[g] - mx);
        ssum += s[g];
    }
    const float inv = 1.0f / ssum;

    float vo[16];
#pragma unroll
    for (int j = 0; j < 16; ++j) vo[j] = 0.f;
#pragma unroll
    for (int g = 0; g < 16; ++g) {
        const float w = s[g] * inv;
        const bf16x8* vp = (const bf16x8*)(kvb + g * 128 + 64 + dq * 16);
        bf16x8 v0 = vp[0], v1 = vp[1];
#pragma unroll
        for (int j = 0; j < 8; ++j) {
            vo[j] += w * b2f(v0[j]);
            vo[8 + j] += w * b2f(v1[j]);
        }
    }

    bf16x8 o0, o1;
#pragma unroll
    for (int j = 0; j < 8; ++j) {
        o0[j] = f2b(vo[j]);
        o1[j] = f2b(vo[8 + j]);
    }
    bf16x8* op = (bf16x8*)(VAL + p * 1024 + (size_t)lane * 16);
    op[0] = o0;
    op[1] = o1;
}

// ---------------------------------------------------------------------------
extern "C" void kernel_launch(void* const* d_in, const int* in_sizes, int n_in,
                              void* d_out, int out_size, void* d_ws,
                              size_t ws_size, hipStream_t stream) {
    const float* x = (const float*)d_in[0];
    const float* y = (const float*)d_in[1];
    const float* Wkv = (const float*)d_in[2];
    const float* bkv = (const float*)d_in[3];
    const float* Wq = (const float*)d_in[4];
    const float* bq = (const float*)d_in[5];
    const float* Wo = (const float*)d_in[6];
    const float* bo = (const float*)d_in[7];
    float* out = (float*)d_out;

    const int D = 1024;
    const int M = 16384;  // B*L

    // workspace layout (142.6 MB total)
    char* ws = (char*)d_ws;
    short* Xb = (short*)(ws);                      // M*D bf16      (33.5 MB)
    short* Yb = (short*)(ws + 33554432);           // M*D bf16      (33.5 MB)
    short* Wkvt = (short*)(ws + 67108864);         // 2D*D bf16     (4 MB)
    short* Wqt = (short*)(ws + 71303168);          // D*D bf16      (2 MB)
    short* Wot = (short*)(ws + 73400320);          // D*D bf16      (2 MB)
    short* KV = (short*)(ws + 75497472);           // M*2D bf16     (67 MB)
    short* Q = Xb;    // Xb dead after kv GEMM
    short* VAL = Yb;  // Yb dead after q GEMM

    const int n = M * D;  // 16777216

    cast2_f32_bf16<<<2 * n / 1024, 256, 0, stream>>>(x, Xb, y, Yb, n);
    transpose_cast2<<<dim3(2 * D / 32, D / 32, 1), dim3(32, 8), 0, stream>>>(
        Wkv, Wkvt, (const float*)0, (short*)0, D, 2 * D);
    transpose_cast2<<<dim3(D / 32, D / 32, 2), dim3(32, 8), 0, stream>>>(
        Wq, Wqt, Wo, Wot, D, D);

    // kv = x @ Wkv + bkv   [16384 x 2048] bf16
    gemm_bt<1><<<dim3(2 * D / BN, M / BM), 512, 0, stream>>>(
        Xb, Wkvt, bkv, KV, M, 2 * D, D);
    // q = y @ Wq + bq      [16384 x 1024] bf16 (into Xb slot)
    gemm_bt<1><<<dim3(D / BN, M / BM), 512, 0, stream>>>(
        Yb, Wqt, bq, Q, M, D, D);
    // attention over heads -> VAL (into Yb slot)
    attn_kernel<<<M / 4, 256, 0, stream>>>(Q, KV, VAL);
    // out = val @ Wo + bo  [16384 x 1024] fp32
    gemm_bt<0><<<dim3(D / BN, M / BM), 512, 0, stream>>>(
        VAL, Wot, bo, out, M, D, D);
}